// Round 8
// baseline (203.375 us; speedup 1.0000x reference)
//
#include <hip/hip_runtime.h>

// ---------------------------------------------------------------------------
// Attention (b=2, sq=skv=2048, dim=1024, H=16, DH=64) for MI355X / gfx950.
// fp32 -> bf16 internal -> fp32 out.  5 dispatches:
//   cvt2 | transposeW | fused QKV GEMM 128x128 (Q*scale, K, V^T) | attn | GEMM out
// R8: attn = 4 waves as (wq 2)x(wkv 2) quadrants of a q64 x kv64 tile.
//     Grid 1024 blocks, 40 KB LDS -> 4 blocks/CU (16 waves/CU, 2x R7 TLP).
//     Static softmax => cross-wkv combine is a plain add at the end.
// ---------------------------------------------------------------------------

typedef __attribute__((ext_vector_type(8))) short short8;   // 8 x bf16
typedef __attribute__((ext_vector_type(4))) short short4v;  // 4 x bf16 (8B)
typedef __attribute__((ext_vector_type(4))) float floatx4;  // MFMA accum

#define QSCALE 0.18033688f  /* 0.125 * log2(e) folded into Q */

#if __has_builtin(__builtin_amdgcn_exp2f)
#define EXP2(x) __builtin_amdgcn_exp2f(x)
#else
#define EXP2(x) exp2f(x)
#endif

__device__ __forceinline__ ushort f2b(float f) {  // fp32 -> bf16 RNE
  union { float f; unsigned u; } x; x.f = f;
  unsigned r = (x.u + 0x7fffu + ((x.u >> 16) & 1u)) >> 16;
  return (ushort)r;
}

// pack two fp32 -> two bf16 in one uint via v_perm (round-half-up)
__device__ __forceinline__ unsigned f2b2(float a, float b) {
  union { float f; unsigned u; } x, y; x.f = a; y.f = b;
  return __builtin_amdgcn_perm(y.u + 0x8000u, x.u + 0x8000u, 0x07060302u);
}

#define GLL(gp, lp)                                                            \
  __builtin_amdgcn_global_load_lds(                                            \
      (const __attribute__((address_space(1))) void*)(gp),                     \
      (__attribute__((address_space(3))) void*)(lp), 16, 0, 0)

// ---------------- fp32 -> bf16 convert, both activations in one grid --------
__global__ void cvt2(const float* __restrict__ a, const float* __restrict__ bsrc,
                     ushort* __restrict__ oa, ushort* __restrict__ ob, int n) {
  int half = gridDim.x >> 1;
  bool lo = (int)blockIdx.x < half;
  const float* in = lo ? a : bsrc;
  ushort* out = lo ? oa : ob;
  int bid = lo ? blockIdx.x : blockIdx.x - half;
  int stride = half * blockDim.x * 4;
  for (int i = (bid * blockDim.x + threadIdx.x) * 4; i < n; i += stride) {
    float4 v = *(const float4*)(in + i);
    uint2 o;
    o.x = f2b2(v.x, v.y);
    o.y = f2b2(v.z, v.w);
    *(uint2*)(out + i) = o;
  }
}

// --------- weight transpose+convert: both W in one grid (K=1024 rows) -------
__global__ void transposeW(const float* __restrict__ Wqkv, ushort* __restrict__ WqkvT,
                           const float* __restrict__ Wout, ushort* __restrict__ WoutT) {
  __shared__ float tile[32][33];
  bool first = blockIdx.x < 96;
  const float* in = first ? Wqkv : Wout;
  ushort* out = first ? WqkvT : WoutT;
  int N = first ? 3072 : 1024;
  int bx = first ? blockIdx.x : blockIdx.x - 96;
  int k0 = blockIdx.y * 32, n0 = bx * 32;
  int tx = threadIdx.x, ty = threadIdx.y;  // 32 x 8
#pragma unroll
  for (int i = 0; i < 32; i += 8)
    tile[ty + i][tx] = in[(size_t)(k0 + ty + i) * N + n0 + tx];
  __syncthreads();
#pragma unroll
  for (int i = 0; i < 32; i += 8)
    out[(size_t)(n0 + ty + i) * 1024 + k0 + tx] = f2b(tile[tx][ty + i]);
}

// ---------------- fused QKV GEMM: 128x128 tile, BK=32, dbuf ------------------
// C cols: [0,1024) Q*QSCALE -> Cq ; [1024,2048) K -> Ck ; [2048,3072) V^T -> Cv
__global__ __launch_bounds__(256, 3) void gemm_qkv(
    const ushort* __restrict__ Aq, const ushort* __restrict__ Akv,
    const ushort* __restrict__ Bt,
    ushort* __restrict__ Cq, ushort* __restrict__ Ck, ushort* __restrict__ Cv) {
  __shared__ __align__(16) ushort As[2][128 * 32];
  __shared__ __align__(16) ushort Bs[2][128 * 32];
  const int n0 = blockIdx.x * 128, m0 = blockIdx.y * 128;
  // col blocks: 0..7 = Q (from x_q), 8..15 = K, 16..23 = V (both from x_kv)
  const ushort* A = (blockIdx.x >= 8) ? Akv : Aq;
  const int t = threadIdx.x;
  const int w = t >> 6, lane = t & 63, dl = lane & 15, g = lane >> 4;
  const int wm = (w >> 1) * 64, wn = (w & 1) * 64;
  const int K = 1024;

  auto stage = [&](int buf, int k0) {
#pragma unroll
    for (int p = 0; p < 2; p++) {
      int j = t + p * 256;
      int row = j >> 2, slot = j & 3, c = (slot - row) & 3;
      GLL(A + (size_t)(m0 + row) * K + k0 + c * 8, &As[buf][j * 8]);
    }
#pragma unroll
    for (int p = 0; p < 2; p++) {
      int j = t + p * 256;
      int row = j >> 2, slot = j & 3, c = (slot - row) & 3;
      GLL(Bt + (size_t)(n0 + row) * K + k0 + c * 8, &Bs[buf][j * 8]);
    }
  };

  const floatx4 fz = {0.f, 0.f, 0.f, 0.f};
  floatx4 acc[4][4];
#pragma unroll
  for (int i = 0; i < 4; i++)
#pragma unroll
    for (int j = 0; j < 4; j++) acc[i][j] = fz;

  stage(0, 0);
  for (int kt = 0; kt < 32; kt++) {
    int cur = kt & 1;
    __builtin_amdgcn_s_waitcnt(0);
    __syncthreads();  // buf[cur] ready; all waves past buf[cur^1] reads
    if (kt + 1 < 32) stage(cur ^ 1, (kt + 1) * 32);
    short8 af[4], bf[4];
#pragma unroll
    for (int mt = 0; mt < 4; mt++) {
      int row = wm + mt * 16 + dl;
      af[mt] = *(const short8*)&As[cur][row * 32 + ((g + row) & 3) * 8];
    }
#pragma unroll
    for (int nt = 0; nt < 4; nt++) {
      int row = wn + nt * 16 + dl;
      bf[nt] = *(const short8*)&Bs[cur][row * 32 + ((g + row) & 3) * 8];
    }
#pragma unroll
    for (int mt = 0; mt < 4; mt++)
#pragma unroll
      for (int nt = 0; nt < 4; nt++)
        acc[mt][nt] = __builtin_amdgcn_mfma_f32_16x16x32_bf16(af[mt], bf[nt], acc[mt][nt], 0, 0, 0);
  }

  // epilogue: row = g*4 + r (+16*mt), col = dl (+16*nt)
#pragma unroll
  for (int mt = 0; mt < 4; mt++)
#pragma unroll
    for (int nt = 0; nt < 4; nt++) {
      int gcol = n0 + wn + nt * 16 + dl;
      int row0 = m0 + wm + mt * 16 + g * 4;
      if (gcol < 1024) {  // Q with folded softmax scale
#pragma unroll
        for (int r = 0; r < 4; r++)
          Cq[(size_t)(row0 + r) * 1024 + gcol] = f2b(acc[mt][nt][r] * QSCALE);
      } else if (gcol < 2048) {
#pragma unroll
        for (int r = 0; r < 4; r++)
          Ck[(size_t)(row0 + r) * 1024 + gcol - 1024] = f2b(acc[mt][nt][r]);
      } else {  // V^T: [b][hd][kv] — 4 consecutive kv, packed store
        uint2 pk;
        pk.x = f2b2(acc[mt][nt][0], acc[mt][nt][1]);
        pk.y = f2b2(acc[mt][nt][2], acc[mt][nt][3]);
        *(uint2*)(Cv + ((size_t)(row0 >> 11) * 1024 + (gcol - 2048)) * 2048 +
                  (row0 & 2047)) = pk;
      }
    }
}

// ---------------- out GEMM: 128x64 tile, BK=64, dbuf, f32 + bias ------------
__global__ __launch_bounds__(256, 3) void gemm_out(
    const ushort* __restrict__ A, const ushort* __restrict__ Bt,
    float* __restrict__ C, const float* __restrict__ bias) {
  __shared__ __align__(16) ushort As[2][128 * 64];
  __shared__ __align__(16) ushort Bs[2][64 * 64];
  const int n0 = blockIdx.x * 64, m0 = blockIdx.y * 128;
  const int t = threadIdx.x;
  const int w = t >> 6, lane = t & 63, dl = lane & 15, g = lane >> 4;
  const int wm = (w >> 1) * 64, wn = (w & 1) * 32;
  const int K = 1024;

  auto stage = [&](int buf, int k0) {
#pragma unroll
    for (int p = 0; p < 4; p++) {
      int j = t + p * 256;
      int row = j >> 3, slot = j & 7, c = (slot - row) & 7;
      GLL(A + (size_t)(m0 + row) * K + k0 + c * 8, &As[buf][j * 8]);
    }
#pragma unroll
    for (int p = 0; p < 2; p++) {
      int j = t + p * 256;
      int row = j >> 3, slot = j & 7, c = (slot - row) & 7;
      GLL(Bt + (size_t)(n0 + row) * K + k0 + c * 8, &Bs[buf][j * 8]);
    }
  };

  const floatx4 fz = {0.f, 0.f, 0.f, 0.f};
  floatx4 acc[4][2];
#pragma unroll
  for (int i = 0; i < 4; i++)
#pragma unroll
    for (int j = 0; j < 2; j++) acc[i][j] = fz;

  stage(0, 0);
  for (int kt = 0; kt < 16; kt++) {
    int cur = kt & 1;
    __builtin_amdgcn_s_waitcnt(0);
    __syncthreads();
    if (kt + 1 < 16) stage(cur ^ 1, (kt + 1) * 64);
#pragma unroll
    for (int ks = 0; ks < 2; ks++) {
      short8 af[4], bf[2];
#pragma unroll
      for (int mt = 0; mt < 4; mt++) {
        int row = wm + mt * 16 + dl;
        af[mt] = *(const short8*)&As[cur][row * 64 + ((ks * 4 + g + row) & 7) * 8];
      }
#pragma unroll
      for (int nt = 0; nt < 2; nt++) {
        int row = wn + nt * 16 + dl;
        bf[nt] = *(const short8*)&Bs[cur][row * 64 + ((ks * 4 + g + row) & 7) * 8];
      }
#pragma unroll
      for (int mt = 0; mt < 4; mt++)
#pragma unroll
        for (int nt = 0; nt < 2; nt++)
          acc[mt][nt] = __builtin_amdgcn_mfma_f32_16x16x32_bf16(af[mt], bf[nt], acc[mt][nt], 0, 0, 0);
    }
  }
#pragma unroll
  for (int mt = 0; mt < 4; mt++)
#pragma unroll
    for (int nt = 0; nt < 2; nt++) {
      int gcol = n0 + wn + nt * 16 + dl;
      int row0 = m0 + wm + mt * 16 + g * 4;
      float badd = bias[gcol];
#pragma unroll
      for (int r = 0; r < 4; r++)
        C[(size_t)(row0 + r) * 1024 + gcol] = acc[mt][nt][r] + badd;
    }
}

// --------------------------- flash attention --------------------------------
// Block: q-tile 64, kv-tile 64; 4 waves = (wq 2) x (wkv 2) quadrants (32q x 32kv
// each).  Static softmax (Q pre-scaled, bare v_exp_f32); partial O/l per wkv
// half combined by plain adds at the end (LDS exchange reusing Ks/Vs).
// LDS: Ks 2x8K + Vs 2x8K + Pq 8K = 40960 B -> 4 blocks/CU; grid 1024 exact.
__global__ __launch_bounds__(256, 4) void attn(
    const ushort* __restrict__ Qb,   // [4096][1024]  (pre-scaled)
    const ushort* __restrict__ Kb,   // [4096][1024]
    const ushort* __restrict__ Vt,   // [2][1024][2048]
    ushort* __restrict__ Ob) {       // [4096][1024]
  __shared__ __align__(16) ushort Ks[2][64 * 64];  // [buf][kv][d]  &7 swizzle
  __shared__ __align__(16) ushort Vs[2][64 * 64];  // [buf][d][kv]  &7 swizzle
  __shared__ __align__(16) ushort Pq[64 * 64];     // [q][kv] 8B slots, xor by q

  const int bh = blockIdx.x, b = bh >> 4, h = bh & 15;
  const int q0 = blockIdx.y * 64;
  const int t = threadIdx.x, w = t >> 6, lane = t & 63, dl = lane & 15, g = lane >> 4;
  const int wq = w & 1, wkv = w >> 1;

  const ushort* Kg = Kb + (size_t)(b * 2048) * 1024 + h * 64;
  const ushort* Vg = Vt + (size_t)(b * 1024 + h * 64) * 2048;

  // Q fragments to registers: bq[nt][ks]; q col = q0 + wq*32 + nt*16 + dl
  short8 bq[2][2];
#pragma unroll
  for (int nt = 0; nt < 2; nt++) {
    int qa = q0 + wq * 32 + nt * 16 + dl;
    const ushort* qrow = Qb + (size_t)(b * 2048 + qa) * 1024 + h * 64;
    bq[nt][0] = *(const short8*)(qrow + g * 8);
    bq[nt][1] = *(const short8*)(qrow + 32 + g * 8);
  }

  auto stageK = [&](int buf, int kv0) {
#pragma unroll
    for (int p = 0; p < 2; p++) {
      int j = t + p * 256;
      int row = j >> 3, slot = j & 7, c = (slot - row) & 7;
      GLL(Kg + (size_t)(kv0 + row) * 1024 + c * 8, &Ks[buf][j * 8]);
    }
  };
  auto stageV = [&](int buf, int kv0) {
#pragma unroll
    for (int p = 0; p < 2; p++) {
      int j = t + p * 256;
      int row = j >> 3, slot = j & 7, c = (slot - row) & 7;
      GLL(Vg + (size_t)row * 2048 + kv0 + c * 8, &Vs[buf][j * 8]);
    }
  };
  stageK(0, 0);
  stageV(0, 0);

  const floatx4 fz = {0.f, 0.f, 0.f, 0.f};
  floatx4 o[4][2];  // O^T partial: d = mtd*16+g*4+r, q = wq*32+nt*16+dl (kv half wkv)
#pragma unroll
  for (int i = 0; i < 4; i++)
#pragma unroll
    for (int n = 0; n < 2; n++) o[i][n] = fz;
  floatx4 l4[2] = {fz, fz};

  for (int it = 0; it < 32; it++) {
    int cur = it & 1;
    __builtin_amdgcn_s_waitcnt(0);
    __syncthreads();  // K/V[cur] ready; all waves done with [cur^1]
    if (it + 1 < 32) { stageK(cur ^ 1, (it + 1) * 64); stageV(cur ^ 1, (it + 1) * 64); }

    // S^T = K @ Q^T over this wave's quadrant: kv rows wkv*32 + mt*16 + dl
    floatx4 s[2][2];
#pragma unroll
    for (int mt = 0; mt < 2; mt++)
#pragma unroll
      for (int nt = 0; nt < 2; nt++) s[mt][nt] = fz;
#pragma unroll
    for (int ks = 0; ks < 2; ks++) {
      short8 a[2];
#pragma unroll
      for (int mt = 0; mt < 2; mt++) {
        int row = wkv * 32 + mt * 16 + dl;
        a[mt] = *(const short8*)&Ks[cur][row * 64 + ((ks * 4 + g + row) & 7) * 8];
      }
#pragma unroll
      for (int mt = 0; mt < 2; mt++)
#pragma unroll
        for (int nt = 0; nt < 2; nt++)
          s[mt][nt] = __builtin_amdgcn_mfma_f32_16x16x32_bf16(a[mt], bq[nt][ks], s[mt][nt], 0, 0, 0);
    }

    // static softmax + vector l accumulate (partial over this kv half)
#pragma unroll
    for (int nt = 0; nt < 2; nt++)
#pragma unroll
      for (int mt = 0; mt < 2; mt++) {
#pragma unroll
        for (int r = 0; r < 4; r++) s[mt][nt][r] = EXP2(s[mt][nt][r]);
        l4[nt] += s[mt][nt];
      }

    // P -> Pq rows q, cols = own kv half (wave-private columns; no barrier)
#pragma unroll
    for (int nt = 0; nt < 2; nt++) {
      int qr = wq * 32 + nt * 16 + dl;
#pragma unroll
      for (int mt = 0; mt < 2; mt++) {
        int kvq = wkv * 8 + mt * 4 + g;  // 8B slot index (4 kv per slot)
        uint2 pk;
        pk.x = f2b2(s[mt][nt][0], s[mt][nt][1]);
        pk.y = f2b2(s[mt][nt][2], s[mt][nt][3]);
        *(uint2*)&Pq[qr * 64 + ((kvq + qr) & 15) * 4] = pk;
      }
    }
    asm volatile("" ::: "memory");

    // O^T += V^T[d][kv half] @ P^T[kv half][q]  (K=32 = whole half)
    short8 av[4], bp[2];
#pragma unroll
    for (int mtd = 0; mtd < 4; mtd++) {
      int row = mtd * 16 + dl;
      av[mtd] = *(const short8*)&Vs[cur][row * 64 + ((wkv * 4 + g + row) & 7) * 8];
    }
#pragma unroll
    for (int nt = 0; nt < 2; nt++) {
      int qr = wq * 32 + nt * 16 + dl;
      int kvq = wkv * 8 + g * 2;
      short4v lo = *(const short4v*)&Pq[qr * 64 + ((kvq + qr) & 15) * 4];
      short4v hi = *(const short4v*)&Pq[qr * 64 + ((kvq + 1 + qr) & 15) * 4];
      bp[nt] = short8{lo.x, lo.y, lo.z, lo.w, hi.x, hi.y, hi.z, hi.w};
    }
#pragma unroll
    for (int mtd = 0; mtd < 4; mtd++)
#pragma unroll
      for (int nt = 0; nt < 2; nt++)
        o[mtd][nt] = __builtin_amdgcn_mfma_f32_16x16x32_bf16(av[mtd], bp[nt], o[mtd][nt], 0, 0, 0);
    asm volatile("" ::: "memory");
  }

  // ---- combine the two kv halves (plain adds; static softmax) ----
  // l: reduce across g lanes first (per q column)
  float lsum[2];
#pragma unroll
  for (int nt = 0; nt < 2; nt++) {
    float l = (l4[nt][0] + l4[nt][1]) + (l4[nt][2] + l4[nt][3]);
    l += __shfl_xor(l, 16);
    l += __shfl_xor(l, 32);
    lsum[nt] = l;
  }

  __syncthreads();  // loop fully done; Ks/Vs reusable
  float* redO = (float*)Ks;  // 4096 floats = 16 KB
  float* redL = (float*)Vs;  // 64 floats used
  if (wkv == 1) {
#pragma unroll
    for (int mtd = 0; mtd < 4; mtd++)
#pragma unroll
      for (int nt = 0; nt < 2; nt++)
        *(floatx4*)&redO[wq * 2048 + lane * 32 + (mtd * 2 + nt) * 4] = o[mtd][nt];
#pragma unroll
    for (int nt = 0; nt < 2; nt++)
      redL[wq * 32 + nt * 16 + dl] = lsum[nt];
  }
  __syncthreads();
  if (wkv == 0) {
    float inv_l[2];
#pragma unroll
    for (int nt = 0; nt < 2; nt++)
      inv_l[nt] = 1.f / (lsum[nt] + redL[wq * 32 + nt * 16 + dl]);
#pragma unroll
    for (int mtd = 0; mtd < 4; mtd++)
#pragma unroll
      for (int nt = 0; nt < 2; nt++)
        o[mtd][nt] += *(const floatx4*)&redO[wq * 2048 + lane * 32 + (mtd * 2 + nt) * 4];
    // normalized O -> Pq as [q][d] (8B slots swizzled by q)
#pragma unroll
    for (int nt = 0; nt < 2; nt++) {
      int qr = wq * 32 + nt * 16 + dl;
#pragma unroll
      for (int mtd = 0; mtd < 4; mtd++) {
        int dq = mtd * 4 + g;
        uint2 pk;
        pk.x = f2b2(o[mtd][nt][0] * inv_l[nt], o[mtd][nt][1] * inv_l[nt]);
        pk.y = f2b2(o[mtd][nt][2] * inv_l[nt], o[mtd][nt][3] * inv_l[nt]);
        *(uint2*)&Pq[qr * 64 + ((dq + qr) & 15) * 4] = pk;
      }
    }
  }
  __syncthreads();
  // all 256 threads: copy Pq (64 q x 64 d) -> global
#pragma unroll
  for (int p = 0; p < 2; p++) {
    int j = t + p * 256;
    int row = j >> 3, c = j & 7;
    short4v lo = *(const short4v*)&Pq[row * 64 + ((2 * c + row) & 15) * 4];
    short4v hi = *(const short4v*)&Pq[row * 64 + ((2 * c + 1 + row) & 15) * 4];
    short8 v = {lo.x, lo.y, lo.z, lo.w, hi.x, hi.y, hi.z, hi.w};
    *(short8*)(Ob + (size_t)(b * 2048 + q0 + row) * 1024 + h * 64 + c * 8) = v;
  }
}

// ---------------------------------------------------------------------------
extern "C" void kernel_launch(void* const* d_in, const int* in_sizes, int n_in,
                              void* d_out, int out_size, void* d_ws, size_t ws_size,
                              hipStream_t stream) {
  const float* x_q  = (const float*)d_in[0];
  const float* x_kv = (const float*)d_in[1];
  const float* Wqkv = (const float*)d_in[2];
  const float* Wout = (const float*)d_in[3];
  const float* bout = (const float*)d_in[4];
  float* out = (float*)d_out;

  char* p = (char*)d_ws;  // 56 MiB total
  ushort* Xq    = (ushort*)p; p += (size_t)4096 * 1024 * 2;
  ushort* Xkv   = (ushort*)p; p += (size_t)4096 * 1024 * 2;
  ushort* WqkvT = (ushort*)p; p += (size_t)3072 * 1024 * 2;
  ushort* WoutT = (ushort*)p; p += (size_t)1024 * 1024 * 2;
  ushort* Qb    = (ushort*)p; p += (size_t)4096 * 1024 * 2;
  ushort* Kb    = (ushort*)p; p += (size_t)4096 * 1024 * 2;
  ushort* Vt    = (ushort*)p; p += (size_t)2 * 1024 * 2048 * 2;
  ushort* Ob    = (ushort*)p; p += (size_t)4096 * 1024 * 2;

  cvt2<<<2048, 256, 0, stream>>>(x_q, x_kv, Xq, Xkv, 4096 * 1024);
  transposeW<<<dim3(128, 32), dim3(32, 8), 0, stream>>>(Wqkv, WqkvT, Wout, WoutT);
  gemm_qkv<<<dim3(24, 32), 256, 0, stream>>>(Xq, Xkv, WqkvT, Qb, Kb, Vt);
  attn<<<dim3(32, 32), 256, 0, stream>>>(Qb, Kb, Vt, Ob);
  gemm_out<<<dim3(16, 32), 256, 0, stream>>>(Ob, WoutT, out, bout);
}

// Round 9
// 196.950 us; speedup vs baseline: 1.0326x; 1.0326x over previous
//
#include <hip/hip_runtime.h>

// ---------------------------------------------------------------------------
// Attention (b=2, sq=skv=2048, dim=1024, H=16, DH=64) for MI355X / gfx950.
// fp32 -> bf16 internal -> fp32 out.  4 dispatches:
//   prep (cvt x2 + transpose W) | fused QKV GEMM | attn | GEMM out
// R9: attn reverted to R7 (best, 57.5us; R8 kv-split regressed).
//     gemm_qkv V^T epilogue now LDS-staged -> coalesced 16B row stores
//     (was 8B/4KB-stride scatter).  cvt2+transposeW merged into one kernel.
// ---------------------------------------------------------------------------

typedef __attribute__((ext_vector_type(8))) short short8;   // 8 x bf16
typedef __attribute__((ext_vector_type(4))) short short4v;  // 4 x bf16 (8B)
typedef __attribute__((ext_vector_type(4))) float floatx4;  // MFMA accum

#define QSCALE 0.18033688f  /* 0.125 * log2(e) folded into Q */

#if __has_builtin(__builtin_amdgcn_exp2f)
#define EXP2(x) __builtin_amdgcn_exp2f(x)
#else
#define EXP2(x) exp2f(x)
#endif

__device__ __forceinline__ ushort f2b(float f) {  // fp32 -> bf16 RNE
  union { float f; unsigned u; } x; x.f = f;
  unsigned r = (x.u + 0x7fffu + ((x.u >> 16) & 1u)) >> 16;
  return (ushort)r;
}

// pack two fp32 -> two bf16 in one uint via v_perm (round-half-up)
__device__ __forceinline__ unsigned f2b2(float a, float b) {
  union { float f; unsigned u; } x, y; x.f = a; y.f = b;
  return __builtin_amdgcn_perm(y.u + 0x8000u, x.u + 0x8000u, 0x07060302u);
}

#define GLL(gp, lp)                                                            \
  __builtin_amdgcn_global_load_lds(                                            \
      (const __attribute__((address_space(1))) void*)(gp),                     \
      (__attribute__((address_space(3))) void*)(lp), 16, 0, 0)

// ---- prep: activations fp32->bf16 (blocks 0..2047) + W transpose (rest) ----
__global__ void prep(const float* __restrict__ xq, const float* __restrict__ xkv,
                     ushort* __restrict__ oq, ushort* __restrict__ okv,
                     const float* __restrict__ Wqkv, ushort* __restrict__ WqkvT,
                     const float* __restrict__ Wout, ushort* __restrict__ WoutT) {
  __shared__ float tile[32][33];
  int bid = blockIdx.x;
  const int n = 4096 * 1024;
  if (bid < 2048) {
    bool lo = bid < 1024;
    const float* in = lo ? xq : xkv;
    ushort* out = lo ? oq : okv;
    int b2 = lo ? bid : bid - 1024;
    int stride = 1024 * 256 * 4;
    for (int i = (b2 * 256 + (int)threadIdx.x) * 4; i < n; i += stride) {
      float4 v = *(const float4*)(in + i);
      uint2 o;
      o.x = f2b2(v.x, v.y);
      o.y = f2b2(v.z, v.w);
      *(uint2*)(out + i) = o;
    }
    return;
  }
  // transpose blocks: 4096 tiles of 32x32 (96+32 cols x 32 rows of k)
  int tb = bid - 2048;               // 0..4095
  int bx = tb & 127, by = tb >> 7;   // bx: 0..95 Wqkv, 96..127 Wout
  bool first = bx < 96;
  const float* in = first ? Wqkv : Wout;
  ushort* out = first ? WqkvT : WoutT;
  int N = first ? 3072 : 1024;
  int bxx = first ? bx : bx - 96;
  int k0 = by * 32, n0 = bxx * 32;
  int tx = threadIdx.x & 31, ty = threadIdx.x >> 5;  // 32 x 8
#pragma unroll
  for (int i = 0; i < 32; i += 8)
    tile[ty + i][tx] = in[(size_t)(k0 + ty + i) * N + n0 + tx];
  __syncthreads();
#pragma unroll
  for (int i = 0; i < 32; i += 8)
    out[(size_t)(n0 + ty + i) * 1024 + k0 + tx] = f2b(tile[tx][ty + i]);
}

// ---------------- fused QKV GEMM: 128x128 tile, BK=32, dbuf ------------------
// C cols: [0,1024) Q*QSCALE -> Cq ; [1024,2048) K -> Ck ; [2048,3072) V^T -> Cv
// V blocks route the C-tile through LDS ([hd][kv], padded) for coalesced
// stores.  smem union: staging (32 KB) / V-epilogue tile (34 KB).
__global__ __launch_bounds__(256, 3) void gemm_qkv(
    const ushort* __restrict__ Aq, const ushort* __restrict__ Akv,
    const ushort* __restrict__ Bt,
    ushort* __restrict__ Cq, ushort* __restrict__ Ck, ushort* __restrict__ Cv) {
  __shared__ __align__(16) ushort smem[17408];  // 34816 B
  ushort* Asb = smem;          // [2][4096]
  ushort* Bsb = smem + 8192;   // [2][4096]
  const int n0 = blockIdx.x * 128, m0 = blockIdx.y * 128;
  // col blocks: 0..7 = Q (from x_q), 8..15 = K, 16..23 = V (both from x_kv)
  const ushort* A = (blockIdx.x >= 8) ? Akv : Aq;
  const int t = threadIdx.x;
  const int w = t >> 6, lane = t & 63, dl = lane & 15, g = lane >> 4;
  const int wm = (w >> 1) * 64, wn = (w & 1) * 64;
  const int K = 1024;

  auto stage = [&](int buf, int k0) {
#pragma unroll
    for (int p = 0; p < 2; p++) {
      int j = t + p * 256;
      int row = j >> 2, slot = j & 3, c = (slot - row) & 3;
      GLL(A + (size_t)(m0 + row) * K + k0 + c * 8, &Asb[buf * 4096 + j * 8]);
    }
#pragma unroll
    for (int p = 0; p < 2; p++) {
      int j = t + p * 256;
      int row = j >> 2, slot = j & 3, c = (slot - row) & 3;
      GLL(Bt + (size_t)(n0 + row) * K + k0 + c * 8, &Bsb[buf * 4096 + j * 8]);
    }
  };

  const floatx4 fz = {0.f, 0.f, 0.f, 0.f};
  floatx4 acc[4][4];
#pragma unroll
  for (int i = 0; i < 4; i++)
#pragma unroll
    for (int j = 0; j < 4; j++) acc[i][j] = fz;

  stage(0, 0);
  for (int kt = 0; kt < 32; kt++) {
    int cur = kt & 1;
    __builtin_amdgcn_s_waitcnt(0);
    __syncthreads();  // buf[cur] ready; all waves past buf[cur^1] reads
    if (kt + 1 < 32) stage(cur ^ 1, (kt + 1) * 32);
    short8 af[4], bf[4];
#pragma unroll
    for (int mt = 0; mt < 4; mt++) {
      int row = wm + mt * 16 + dl;
      af[mt] = *(const short8*)&Asb[cur * 4096 + row * 32 + ((g + row) & 3) * 8];
    }
#pragma unroll
    for (int nt = 0; nt < 4; nt++) {
      int row = wn + nt * 16 + dl;
      bf[nt] = *(const short8*)&Bsb[cur * 4096 + row * 32 + ((g + row) & 3) * 8];
    }
#pragma unroll
    for (int mt = 0; mt < 4; mt++)
#pragma unroll
      for (int nt = 0; nt < 4; nt++)
        acc[mt][nt] = __builtin_amdgcn_mfma_f32_16x16x32_bf16(af[mt], bf[nt], acc[mt][nt], 0, 0, 0);
  }

  if (blockIdx.x < 16) {
    // direct store: row = g*4 + r (+16*mt), col = dl (+16*nt)
#pragma unroll
    for (int mt = 0; mt < 4; mt++)
#pragma unroll
      for (int nt = 0; nt < 4; nt++) {
        int gcol = n0 + wn + nt * 16 + dl;
        int row0 = m0 + wm + mt * 16 + g * 4;
        if (gcol < 1024) {  // Q with folded softmax scale
#pragma unroll
          for (int r = 0; r < 4; r++)
            Cq[(size_t)(row0 + r) * 1024 + gcol] = f2b(acc[mt][nt][r] * QSCALE);
        } else {
#pragma unroll
          for (int r = 0; r < 4; r++)
            Ck[(size_t)(row0 + r) * 1024 + gcol - 1024] = f2b(acc[mt][nt][r]);
        }
      }
  } else {
    // V^T via LDS: smem tile [n-local 128][m-local, stride 136] bf16
    __syncthreads();  // all staging reads done; smem reusable
#pragma unroll
    for (int mt = 0; mt < 4; mt++)
#pragma unroll
      for (int nt = 0; nt < 4; nt++) {
        int ncol = wn + nt * 16 + dl;     // hd-local
        int mrow = wm + mt * 16 + g * 4;  // kv-local (4 consecutive)
        uint2 pk;
        pk.x = f2b2(acc[mt][nt][0], acc[mt][nt][1]);
        pk.y = f2b2(acc[mt][nt][2], acc[mt][nt][3]);
        *(uint2*)&smem[ncol * 136 + mrow] = pk;
      }
    __syncthreads();
    // coalesced: Cv[b][hd][kv], 2048 chunks of 16B (128 rows x 16 chunks)
    int hd0 = n0 - 2048;            // 0..1023
    int bb = m0 >> 11;              // batch
    int kv0 = m0 & 2047;
#pragma unroll
    for (int p = 0; p < 8; p++) {
      int j = t + p * 256;
      int row = j >> 4, c = j & 15;
      short8 v = *(const short8*)&smem[row * 136 + c * 8];
      *(short8*)(Cv + ((size_t)(bb * 1024 + hd0 + row)) * 2048 + kv0 + c * 8) = v;
    }
  }
}

// ---------------- out GEMM: 128x64 tile, BK=64, dbuf, f32 + bias ------------
__global__ __launch_bounds__(256, 3) void gemm_out(
    const ushort* __restrict__ A, const ushort* __restrict__ Bt,
    float* __restrict__ C, const float* __restrict__ bias) {
  __shared__ __align__(16) ushort As[2][128 * 64];
  __shared__ __align__(16) ushort Bs[2][64 * 64];
  const int n0 = blockIdx.x * 64, m0 = blockIdx.y * 128;
  const int t = threadIdx.x;
  const int w = t >> 6, lane = t & 63, dl = lane & 15, g = lane >> 4;
  const int wm = (w >> 1) * 64, wn = (w & 1) * 32;
  const int K = 1024;

  auto stage = [&](int buf, int k0) {
#pragma unroll
    for (int p = 0; p < 4; p++) {
      int j = t + p * 256;
      int row = j >> 3, slot = j & 7, c = (slot - row) & 7;
      GLL(A + (size_t)(m0 + row) * K + k0 + c * 8, &As[buf][j * 8]);
    }
#pragma unroll
    for (int p = 0; p < 2; p++) {
      int j = t + p * 256;
      int row = j >> 3, slot = j & 7, c = (slot - row) & 7;
      GLL(Bt + (size_t)(n0 + row) * K + k0 + c * 8, &Bs[buf][j * 8]);
    }
  };

  const floatx4 fz = {0.f, 0.f, 0.f, 0.f};
  floatx4 acc[4][2];
#pragma unroll
  for (int i = 0; i < 4; i++)
#pragma unroll
    for (int j = 0; j < 2; j++) acc[i][j] = fz;

  stage(0, 0);
  for (int kt = 0; kt < 16; kt++) {
    int cur = kt & 1;
    __builtin_amdgcn_s_waitcnt(0);
    __syncthreads();
    if (kt + 1 < 16) stage(cur ^ 1, (kt + 1) * 64);
#pragma unroll
    for (int ks = 0; ks < 2; ks++) {
      short8 af[4], bf[2];
#pragma unroll
      for (int mt = 0; mt < 4; mt++) {
        int row = wm + mt * 16 + dl;
        af[mt] = *(const short8*)&As[cur][row * 64 + ((ks * 4 + g + row) & 7) * 8];
      }
#pragma unroll
      for (int nt = 0; nt < 2; nt++) {
        int row = wn + nt * 16 + dl;
        bf[nt] = *(const short8*)&Bs[cur][row * 64 + ((ks * 4 + g + row) & 7) * 8];
      }
#pragma unroll
      for (int mt = 0; mt < 4; mt++)
#pragma unroll
        for (int nt = 0; nt < 2; nt++)
          acc[mt][nt] = __builtin_amdgcn_mfma_f32_16x16x32_bf16(af[mt], bf[nt], acc[mt][nt], 0, 0, 0);
    }
  }
#pragma unroll
  for (int mt = 0; mt < 4; mt++)
#pragma unroll
    for (int nt = 0; nt < 2; nt++) {
      int gcol = n0 + wn + nt * 16 + dl;
      int row0 = m0 + wm + mt * 16 + g * 4;
      float badd = bias[gcol];
#pragma unroll
      for (int r = 0; r < 4; r++)
        C[(size_t)(row0 + r) * 1024 + gcol] = acc[mt][nt][r] + badd;
    }
}

// --------------------------- flash attention (R7 best) -----------------------
// Block: 128 q of one (b,h); 4 waves x 32 q-cols (2 nt tiles); kv-tile 64,
// dbuf K/V, 1 barrier/iter.  Q in regs (pre-scaled).  Static softmax with
// bare v_exp_f32.  LDS: Ks 16K + Vs 16K + Pq 16K = 48 KB.
__global__ __launch_bounds__(256, 2) void attn(
    const ushort* __restrict__ Qb,   // [4096][1024]  (pre-scaled)
    const ushort* __restrict__ Kb,   // [4096][1024]
    const ushort* __restrict__ Vt,   // [2][1024][2048]
    ushort* __restrict__ Ob) {       // [4096][1024]
  __shared__ __align__(16) ushort Ks[2][64 * 64];  // [buf][kv][d]  &7 swizzle
  __shared__ __align__(16) ushort Vs[2][64 * 64];  // [buf][d][kv]  &7 swizzle
  __shared__ __align__(16) ushort Pq[128 * 64];    // P / O, 8B-slot xor by row

  const int bh = blockIdx.x, b = bh >> 4, h = bh & 15;
  const int q0 = blockIdx.y * 128;
  const int t = threadIdx.x, w = t >> 6, lane = t & 63, dl = lane & 15, g = lane >> 4;

  const ushort* Kg = Kb + (size_t)(b * 2048) * 1024 + h * 64;
  const ushort* Vg = Vt + (size_t)(b * 1024 + h * 64) * 2048;

  // Q fragments to registers: bq[nt][ks], q col = w*32 + nt*16 + dl
  short8 bq[2][2];
#pragma unroll
  for (int nt = 0; nt < 2; nt++) {
    int qa = q0 + w * 32 + nt * 16 + dl;
    const ushort* qrow = Qb + (size_t)(b * 2048 + qa) * 1024 + h * 64;
    bq[nt][0] = *(const short8*)(qrow + g * 8);
    bq[nt][1] = *(const short8*)(qrow + 32 + g * 8);
  }

  auto stageK = [&](int buf, int kv0) {
#pragma unroll
    for (int p = 0; p < 2; p++) {
      int j = t + p * 256;
      int row = j >> 3, slot = j & 7, c = (slot - row) & 7;
      GLL(Kg + (size_t)(kv0 + row) * 1024 + c * 8, &Ks[buf][j * 8]);
    }
  };
  auto stageV = [&](int buf, int kv0) {
#pragma unroll
    for (int p = 0; p < 2; p++) {
      int j = t + p * 256;
      int row = j >> 3, slot = j & 7, c = (slot - row) & 7;
      GLL(Vg + (size_t)row * 2048 + kv0 + c * 8, &Vs[buf][j * 8]);
    }
  };
  stageK(0, 0);
  stageV(0, 0);

  const floatx4 fz = {0.f, 0.f, 0.f, 0.f};
  floatx4 o[4][2];
#pragma unroll
  for (int i = 0; i < 4; i++)
#pragma unroll
    for (int n = 0; n < 2; n++) o[i][n] = fz;
  floatx4 l4[2] = {fz, fz};  // vector l accumulators

  for (int it = 0; it < 32; it++) {
    int cur = it & 1;
    __builtin_amdgcn_s_waitcnt(0);
    __syncthreads();  // K/V[cur] ready; all waves done with [cur^1]
    if (it + 1 < 32) { stageK(cur ^ 1, (it + 1) * 64); stageV(cur ^ 1, (it + 1) * 64); }

    // S^T = K @ Q^T : 16 MFMA from 8 K-frags (2x reuse) + reg Q
    floatx4 s[4][2];
#pragma unroll
    for (int mt = 0; mt < 4; mt++)
#pragma unroll
      for (int nt = 0; nt < 2; nt++) s[mt][nt] = fz;
#pragma unroll
    for (int ks = 0; ks < 2; ks++) {
      short8 a[4];
#pragma unroll
      for (int mt = 0; mt < 4; mt++) {
        int row = mt * 16 + dl;
        a[mt] = *(const short8*)&Ks[cur][row * 64 + ((ks * 4 + g + row) & 7) * 8];
      }
#pragma unroll
      for (int mt = 0; mt < 4; mt++)
#pragma unroll
        for (int nt = 0; nt < 2; nt++)
          s[mt][nt] = __builtin_amdgcn_mfma_f32_16x16x32_bf16(a[mt], bq[nt][ks], s[mt][nt], 0, 0, 0);
    }

    // static softmax (Q pre-scaled -> bare v_exp_f32); vector l accumulate
#pragma unroll
    for (int nt = 0; nt < 2; nt++)
#pragma unroll
      for (int mt = 0; mt < 4; mt++) {
#pragma unroll
        for (int r = 0; r < 4; r++) s[mt][nt][r] = EXP2(s[mt][nt][r]);
        l4[nt] += s[mt][nt];
      }

    // P -> LDS rows q (wave-private rows), packed 4 kv per 8B slot
#pragma unroll
    for (int nt = 0; nt < 2; nt++) {
      int qr = w * 32 + nt * 16 + dl;
#pragma unroll
      for (int mt = 0; mt < 4; mt++) {
        uint2 pk;
        pk.x = f2b2(s[mt][nt][0], s[mt][nt][1]);
        pk.y = f2b2(s[mt][nt][2], s[mt][nt][3]);
        *(uint2*)&Pq[qr * 64 + ((mt * 4 + g + qr) & 15) * 4] = pk;
      }
    }
    asm volatile("" ::: "memory");

    // O^T += V^T @ P^T : 16 MFMA from 8 V-frags (2x reuse)
#pragma unroll
    for (int ks2 = 0; ks2 < 2; ks2++) {
      short8 av[4], bp[2];
#pragma unroll
      for (int mtd = 0; mtd < 4; mtd++) {
        int row = mtd * 16 + dl;
        av[mtd] = *(const short8*)&Vs[cur][row * 64 + ((ks2 * 4 + g + row) & 7) * 8];
      }
#pragma unroll
      for (int nt = 0; nt < 2; nt++) {
        int qr = w * 32 + nt * 16 + dl;
        int sq = ks2 * 8 + 2 * g;
        short4v lo = *(const short4v*)&Pq[qr * 64 + ((sq + qr) & 15) * 4];
        short4v hi = *(const short4v*)&Pq[qr * 64 + ((sq + 1 + qr) & 15) * 4];
        bp[nt] = short8{lo.x, lo.y, lo.z, lo.w, hi.x, hi.y, hi.z, hi.w};
      }
#pragma unroll
      for (int mtd = 0; mtd < 4; mtd++)
#pragma unroll
        for (int nt = 0; nt < 2; nt++)
          o[mtd][nt] = __builtin_amdgcn_mfma_f32_16x16x32_bf16(av[mtd], bp[nt], o[mtd][nt], 0, 0, 0);
    }
    asm volatile("" ::: "memory");
  }

  // l: horizontal + cross-lane (4 g-lanes of each q column)
  float inv_l[2];
#pragma unroll
  for (int nt = 0; nt < 2; nt++) {
    float l = (l4[nt][0] + l4[nt][1]) + (l4[nt][2] + l4[nt][3]);
    l += __shfl_xor(l, 16);
    l += __shfl_xor(l, 32);
    inv_l[nt] = 1.f / l;
  }

  // epilogue: normalize, O^T -> O via Pq (wave-private rows), write bf16
#pragma unroll
  for (int nt = 0; nt < 2; nt++) {
    int qr = w * 32 + nt * 16 + dl;
#pragma unroll
    for (int mtd = 0; mtd < 4; mtd++) {
      uint2 pk;
      pk.x = f2b2(o[mtd][nt][0] * inv_l[nt], o[mtd][nt][1] * inv_l[nt]);
      pk.y = f2b2(o[mtd][nt][2] * inv_l[nt], o[mtd][nt][3] * inv_l[nt]);
      *(uint2*)&Pq[qr * 64 + ((mtd * 4 + g + qr) & 15) * 4] = pk;
    }
  }
  asm volatile("" ::: "memory");
#pragma unroll
  for (int p = 0; p < 4; p++) {
    int j = lane + p * 64;
    int r32 = j >> 3, c = j & 7;  // 32 q rows x 8 chunks per wave
    int qr = w * 32 + r32;
    short4v lo = *(const short4v*)&Pq[qr * 64 + ((2 * c + qr) & 15) * 4];
    short4v hi = *(const short4v*)&Pq[qr * 64 + ((2 * c + 1 + qr) & 15) * 4];
    short8 v = {lo.x, lo.y, lo.z, lo.w, hi.x, hi.y, hi.z, hi.w};
    *(short8*)(Ob + (size_t)(b * 2048 + q0 + qr) * 1024 + h * 64 + c * 8) = v;
  }
}

// ---------------------------------------------------------------------------
extern "C" void kernel_launch(void* const* d_in, const int* in_sizes, int n_in,
                              void* d_out, int out_size, void* d_ws, size_t ws_size,
                              hipStream_t stream) {
  const float* x_q  = (const float*)d_in[0];
  const float* x_kv = (const float*)d_in[1];
  const float* Wqkv = (const float*)d_in[2];
  const float* Wout = (const float*)d_in[3];
  const float* bout = (const float*)d_in[4];
  float* out = (float*)d_out;

  char* p = (char*)d_ws;  // 56 MiB total
  ushort* Xq    = (ushort*)p; p += (size_t)4096 * 1024 * 2;
  ushort* Xkv   = (ushort*)p; p += (size_t)4096 * 1024 * 2;
  ushort* WqkvT = (ushort*)p; p += (size_t)3072 * 1024 * 2;
  ushort* WoutT = (ushort*)p; p += (size_t)1024 * 1024 * 2;
  ushort* Qb    = (ushort*)p; p += (size_t)4096 * 1024 * 2;
  ushort* Kb    = (ushort*)p; p += (size_t)4096 * 1024 * 2;
  ushort* Vt    = (ushort*)p; p += (size_t)2 * 1024 * 2048 * 2;
  ushort* Ob    = (ushort*)p; p += (size_t)4096 * 1024 * 2;

  prep<<<6144, 256, 0, stream>>>(x_q, x_kv, Xq, Xkv, Wqkv, WqkvT, Wout, WoutT);
  gemm_qkv<<<dim3(24, 32), 256, 0, stream>>>(Xq, Xkv, WqkvT, Qb, Kb, Vt);
  attn<<<dim3(32, 16), 256, 0, stream>>>(Qb, Kb, Vt, Ob);
  gemm_out<<<dim3(16, 32), 256, 0, stream>>>(Ob, WoutT, out, bout);
}